// Round 1
// baseline (2092.297 us; speedup 1.0000x reference)
//
#include <hip/hip_runtime.h>
#include <cstdint>
#include <cstddef>

typedef unsigned short u16;
typedef __attribute__((ext_vector_type(8))) __bf16 bf16x8;
typedef __attribute__((ext_vector_type(4))) float f32x4;

union B8 { bf16x8 v; uint4 q; unsigned long long u[2]; u16 s[8]; };

__device__ __forceinline__ u16 f2b(float f) {
  union { float f; unsigned u; } x; x.f = f;
  unsigned r = x.u + 0x7fffu + ((x.u >> 16) & 1u);
  return (u16)(r >> 16);
}
__device__ __forceinline__ float b2f(u16 s) {
  union { unsigned u; float f; } x; x.u = ((unsigned)s) << 16;
  return x.f;
}

#define TT 2048
#define HH 2048
#define NH 16
#define NKV 4
#define HD 128
#define NE 8
#define FF 4096

// ---------------- rmsnorm (fp32 in -> bf16 out) ----------------
__global__ __launch_bounds__(256) void rmsnorm_k(const float* __restrict__ x, const float* __restrict__ w,
                                                 u16* __restrict__ out) {
  int row = blockIdx.x, tid = threadIdx.x;
  const float* xr = x + (size_t)row * HH;
  float xv[8]; float ss = 0.f;
  #pragma unroll
  for (int i = 0; i < 8; ++i) { xv[i] = xr[tid + i*256]; ss += xv[i]*xv[i]; }
  #pragma unroll
  for (int off = 1; off < 64; off <<= 1) ss += __shfl_xor(ss, off);
  __shared__ float red[4];
  if ((tid & 63) == 0) red[tid >> 6] = ss;
  __syncthreads();
  float rs = rsqrtf((red[0]+red[1]+red[2]+red[3]) * (1.f/HH) + 1e-6f);
  u16* orow = out + (size_t)row * HH;
  #pragma unroll
  for (int i = 0; i < 8; ++i) {
    int h = tid + i*256;
    orow[h] = f2b(xv[i]*rs*w[h]);
  }
}

// ---------------- generic GEMM: C[M,N] = A_bf16[M,K] @ W_f32[K,N] ----------------
// MODE 0: f32 out
// MODE 1: bf16 out
// MODE 2: f32 out = acc + res_f32[idx]        (aux = residual)
// MODE 3: bf16 out = silu(b2f(aux_u16[idx])) * acc   (aux = gate, bf16)
// MODE 4: f32 out[idx] += aux_f32[row] * acc  (aux = per-row scale)
#define BM 128
#define BN 128
#define BK 32
#define SA 40
#define SB 36

template<int MODE, bool SCHED>
__global__ __launch_bounds__(256) void gemm_k(
    const u16* __restrict__ A, const float* __restrict__ W,
    void* __restrict__ outp, const void* __restrict__ aux,
    const int* __restrict__ sched, int M, int N, int K, size_t wstride)
{
  int row0, rowEnd;
  if constexpr (SCHED) {
    int nmb = sched[0];
    int by = blockIdx.y;
    if (by >= nmb) return;
    int e = sched[1 + by*3];
    row0   = sched[2 + by*3];
    rowEnd = sched[3 + by*3];
    W += (size_t)e * wstride;
    (void)M;
  } else {
    row0 = blockIdx.y * BM;
    rowEnd = M;
  }
  int n0 = blockIdx.x * BN;
  int tid = threadIdx.x;
  int wave = tid >> 6, lane = tid & 63, quad = lane >> 4, lm = lane & 15;
  int wr = wave >> 1, wc = wave & 1;

  __shared__ u16 As[BM*SA];
  __shared__ u16 Bs[BN*SB];

  f32x4 acc[4][4];
  f32x4 z = {0.f,0.f,0.f,0.f};
  #pragma unroll
  for (int i = 0; i < 4; ++i)
    #pragma unroll
    for (int j = 0; j < 4; ++j) acc[i][j] = z;

  int bn = tid & 127, bkh = tid >> 7;

  for (int k0 = 0; k0 < K; k0 += BK) {
    // stage A (bf16, 128x32), vectorized
    #pragma unroll
    for (int it = 0; it < 2; ++it) {
      int idx = tid + it*256;
      int row = idx >> 2, ch = idx & 3;
      int grow = row0 + row;
      uint4 val = {0,0,0,0};
      if (grow < rowEnd) val = *(const uint4*)(A + (size_t)grow*K + k0 + ch*8);
      *(uint4*)(&As[row*SA + ch*8]) = val;
    }
    // stage B (fp32 -> bf16, transpose to [n][k])
    {
      const float* wp = W + (size_t)(k0 + bkh*16)*N + n0 + bn;
      u16* bp = &Bs[bn*SB + bkh*16];
      #pragma unroll
      for (int kk = 0; kk < 16; kk += 2) {
        float w0 = wp[(size_t)kk * N];
        float w1 = wp[(size_t)(kk+1) * N];
        unsigned pk = (unsigned)f2b(w0) | ((unsigned)f2b(w1) << 16);
        *(unsigned*)(bp + kk) = pk;
      }
    }
    __syncthreads();
    B8 af[4], bfr[4];
    #pragma unroll
    for (int mt = 0; mt < 4; ++mt)
      af[mt].q = *(const uint4*)(&As[(wr*64 + mt*16 + lm)*SA + quad*8]);
    #pragma unroll
    for (int nt = 0; nt < 4; ++nt) {
      const u16* p = &Bs[(wc*64 + nt*16 + lm)*SB + quad*8];
      bfr[nt].u[0] = *(const unsigned long long*)p;
      bfr[nt].u[1] = *(const unsigned long long*)(p + 4);
    }
    #pragma unroll
    for (int mt = 0; mt < 4; ++mt)
      #pragma unroll
      for (int nt = 0; nt < 4; ++nt)
        acc[mt][nt] = __builtin_amdgcn_mfma_f32_16x16x32_bf16(af[mt].v, bfr[nt].v, acc[mt][nt], 0, 0, 0);
    __syncthreads();
  }

  #pragma unroll
  for (int mt = 0; mt < 4; ++mt) {
    int rbase = row0 + wr*64 + mt*16 + quad*4;
    #pragma unroll
    for (int nt = 0; nt < 4; ++nt) {
      int gcol = n0 + wc*64 + nt*16 + lm;
      #pragma unroll
      for (int r = 0; r < 4; ++r) {
        int rr = rbase + r;
        if (rr >= rowEnd) continue;
        size_t idx = (size_t)rr * N + gcol;
        float val = acc[mt][nt][r];
        if constexpr (MODE == 0) ((float*)outp)[idx] = val;
        else if constexpr (MODE == 1) ((u16*)outp)[idx] = f2b(val);
        else if constexpr (MODE == 2) ((float*)outp)[idx] = val + ((const float*)aux)[idx];
        else if constexpr (MODE == 3) {
          float gg = b2f(((const u16*)aux)[idx]);
          float s = gg / (1.f + __expf(-gg));
          ((u16*)outp)[idx] = f2b(s * val);
        } else if constexpr (MODE == 4) {
          float sg = ((const float*)aux)[rr];
          ((float*)outp)[idx] += sg * val;
        }
      }
    }
  }
}

// ---------------- rope (f32 in -> bf16 out) ----------------
__global__ __launch_bounds__(256) void rope_k(const float* __restrict__ in, const int* __restrict__ pos,
                                              u16* __restrict__ out, int nheads)
{
  int gid = blockIdx.x*256 + threadIdx.x;
  int i = gid & 63;
  int hd = (gid >> 6) % nheads;
  int t = gid / (64*nheads);
  size_t base = ((size_t)t*nheads + hd)*HD;
  float x1 = in[base + i], x2 = in[base + 64 + i];
  float inv = expf((float)i * -0.21586735246819178f); // ln(1e6)/64
  float s, c;
  sincosf((float)pos[t] * inv, &s, &c);
  out[base + i]      = f2b(x1*c - x2*s);
  out[base + 64 + i] = f2b(x2*c + x1*s);
}

// ---------------- flash attention ----------------
#define ASK 136
#define ASV 36
__global__ __launch_bounds__(256) void attn_k(
  const u16* __restrict__ q, const u16* __restrict__ k, const u16* __restrict__ v,
  u16* __restrict__ o)
{
  int h = blockIdx.y;
  int q0 = blockIdx.x * 64;
  int kvh = h >> 2;
  int tid = threadIdx.x, wave = tid >> 6, lane = tid & 63, quad = lane >> 4, lm = lane & 15;

  __shared__ u16 Ks[32*ASK];
  __shared__ u16 VTs[128*ASV];
  __shared__ u16 Ps[4][16*ASV];

  B8 qf[4];
  {
    int tq = q0 + wave*16 + lm;
    const u16* qp = q + ((size_t)tq*NH + h)*HD;
    #pragma unroll
    for (int ks = 0; ks < 4; ++ks) qf[ks].q = *(const uint4*)(qp + ks*32 + quad*8);
  }

  f32x4 oacc[8];
  f32x4 z = {0.f,0.f,0.f,0.f};
  #pragma unroll
  for (int i = 0; i < 8; ++i) oacc[i] = z;
  float m_run[4], l_run[4];
  #pragma unroll
  for (int r = 0; r < 4; ++r) { m_run[r] = -1e30f; l_run[r] = 0.f; }

  const float scale = 0.08838834764831845f; // 1/sqrt(128)
  int send = q0 + 63;
  int trow = q0 + wave*16 + quad*4;

  for (int s0 = 0; s0 <= send; s0 += 32) {
    __syncthreads();
    #pragma unroll
    for (int it = 0; it < 2; ++it) {  // stage K tile 32x128
      int idx = tid + it*256;
      int row = idx >> 4, ch = idx & 15;
      *(uint4*)(&Ks[row*ASK + ch*8]) =
        *(const uint4*)(k + ((size_t)(s0+row)*NKV + kvh)*HD + ch*8);
    }
    {  // stage V^T tile 128x32
      int d = tid & 127, sh = tid >> 7;
      const u16* vp = v + ((size_t)(s0 + sh*16)*NKV + kvh)*HD + d;
      u16* wp2 = &VTs[d*ASV + sh*16];
      #pragma unroll
      for (int ss = 0; ss < 16; ss += 2) {
        u16 a = vp[(size_t)ss*NKV*HD];
        u16 b = vp[(size_t)(ss+1)*NKV*HD];
        *(unsigned*)(wp2 + ss) = (unsigned)a | ((unsigned)b << 16);
      }
    }
    __syncthreads();
    // QK^T : 16 rows x 32 cols
    f32x4 sf[2]; sf[0] = z; sf[1] = z;
    #pragma unroll
    for (int nt = 0; nt < 2; ++nt)
      #pragma unroll
      for (int ks = 0; ks < 4; ++ks) {
        B8 kf;
        kf.q = *(const uint4*)(&Ks[(nt*16+lm)*ASK + ks*32 + quad*8]);
        sf[nt] = __builtin_amdgcn_mfma_f32_16x16x32_bf16(qf[ks].v, kf.v, sf[nt], 0, 0, 0);
      }
    // online softmax
    float alpha[4];
    #pragma unroll
    for (int r = 0; r < 4; ++r) {
      int t = trow + r;
      float v0 = sf[0][r]*scale; if (s0 + lm > t) v0 = -1e30f;
      float v1 = sf[1][r]*scale; if (s0 + 16 + lm > t) v1 = -1e30f;
      float rm = fmaxf(v0, v1);
      #pragma unroll
      for (int off = 1; off < 16; off <<= 1) rm = fmaxf(rm, __shfl_xor(rm, off));
      float mn = fmaxf(m_run[r], rm);
      float al = __expf(m_run[r] - mn);
      float p0 = __expf(v0 - mn);
      float p1 = __expf(v1 - mn);
      float rs = p0 + p1;
      #pragma unroll
      for (int off = 1; off < 16; off <<= 1) rs += __shfl_xor(rs, off);
      l_run[r] = l_run[r]*al + rs;
      m_run[r] = mn;
      alpha[r] = al;
      Ps[wave][(quad*4+r)*ASV + lm]      = f2b(p0);
      Ps[wave][(quad*4+r)*ASV + 16 + lm] = f2b(p1);
    }
    #pragma unroll
    for (int dt = 0; dt < 8; ++dt) {
      f32x4 t4 = oacc[dt];
      t4[0] *= alpha[0]; t4[1] *= alpha[1]; t4[2] *= alpha[2]; t4[3] *= alpha[3];
      oacc[dt] = t4;
    }
    __syncthreads();
    // P @ V
    B8 pf;
    {
      const u16* pp = &Ps[wave][lm*ASV + quad*8];
      pf.u[0] = *(const unsigned long long*)pp;
      pf.u[1] = *(const unsigned long long*)(pp + 4);
    }
    #pragma unroll
    for (int dt = 0; dt < 8; ++dt) {
      B8 vf;
      const u16* vp2 = &VTs[(dt*16+lm)*ASV + quad*8];
      vf.u[0] = *(const unsigned long long*)vp2;
      vf.u[1] = *(const unsigned long long*)(vp2 + 4);
      oacc[dt] = __builtin_amdgcn_mfma_f32_16x16x32_bf16(pf.v, vf.v, oacc[dt], 0, 0, 0);
    }
  }
  #pragma unroll
  for (int r = 0; r < 4; ++r) {
    float inv = 1.f / l_run[r];
    int t = trow + r;
    u16* op = o + (size_t)t*(NH*HD) + h*HD;
    #pragma unroll
    for (int dt = 0; dt < 8; ++dt) op[dt*16 + lm] = f2b(oacc[dt][r]*inv);
  }
}

// ---------------- router (fp32 rmsnorm recompute for exact top-2) ----------------
__global__ __launch_bounds__(256) void router_k(
  const float* __restrict__ hidden, const float* __restrict__ ln2,
  const float* __restrict__ rw, const float* __restrict__ wsg,
  int* __restrict__ topi, float* __restrict__ topw, int* __restrict__ cnt,
  float* __restrict__ sgate)
{
  int t = blockIdx.x, tid = threadIdx.x;
  const float* xr = hidden + (size_t)t*HH;
  float xv[8]; float ss = 0.f;
  #pragma unroll
  for (int i = 0; i < 8; ++i) { xv[i] = xr[tid + i*256]; ss += xv[i]*xv[i]; }
  #pragma unroll
  for (int off = 1; off < 64; off <<= 1) ss += __shfl_xor(ss, off);
  __shared__ float redA[4];
  if ((tid & 63) == 0) redA[tid >> 6] = ss;
  __syncthreads();
  float rs = rsqrtf((redA[0]+redA[1]+redA[2]+redA[3]) * (1.f/HH) + 1e-6f);
  float acc[8] = {0,0,0,0,0,0,0,0};
  float accg = 0.f;
  #pragma unroll
  for (int i = 0; i < 8; ++i) {
    int hh = tid + i*256;
    float x = xv[i]*rs*ln2[hh];
    const float* rp = rw + (size_t)hh*NE;
    #pragma unroll
    for (int e = 0; e < NE; ++e) acc[e] += x*rp[e];
    accg += x*wsg[hh];
  }
  #pragma unroll
  for (int off = 1; off < 64; off <<= 1) {
    #pragma unroll
    for (int e = 0; e < NE; ++e) acc[e] += __shfl_xor(acc[e], off);
    accg += __shfl_xor(accg, off);
  }
  __shared__ float redB[4][9];
  if ((tid & 63) == 0) {
    #pragma unroll
    for (int e = 0; e < NE; ++e) redB[tid >> 6][e] = acc[e];
    redB[tid >> 6][8] = accg;
  }
  __syncthreads();
  if (tid == 0) {
    float l[8];
    #pragma unroll
    for (int e = 0; e < NE; ++e) l[e] = redB[0][e]+redB[1][e]+redB[2][e]+redB[3][e];
    float g = redB[0][8]+redB[1][8]+redB[2][8]+redB[3][8];
    int i0 = 0;
    for (int e = 1; e < NE; ++e) if (l[e] > l[i0]) i0 = e;
    int i1 = (i0 == 0) ? 1 : 0;
    for (int e = 0; e < NE; ++e) if (e != i0 && l[e] > l[i1]) i1 = e;
    float m = fmaxf(l[i0], l[i1]);
    float e0 = expf(l[i0]-m), e1 = expf(l[i1]-m);
    float sw = e0 + e1;
    topi[t*2] = i0; topi[t*2+1] = i1;
    topw[t*2] = e0/sw; topw[t*2+1] = e1/sw;
    atomicAdd(&cnt[i0], 1); atomicAdd(&cnt[i1], 1);
    sgate[t] = 1.f/(1.f + expf(-g));
  }
}

// ---------------- MoE schedule ----------------
__global__ void sched_k(const int* __restrict__ cnt, int* __restrict__ offs, int* __restrict__ sched)
{
  if (threadIdx.x != 0 || blockIdx.x != 0) return;
  int o = 0, nb = 0;
  for (int e = 0; e < NE; ++e) {
    offs[e] = o;
    int c = cnt[e];
    for (int r = 0; r < c; r += BM) {
      sched[1 + nb*3] = e;
      sched[2 + nb*3] = o + r;
      sched[3 + nb*3] = o + ((r + BM < c) ? (r + BM) : c);
      nb++;
    }
    o += c;
  }
  offs[NE] = o;
  sched[0] = nb;
}

__global__ __launch_bounds__(256) void assign_k(const int* __restrict__ topi, const int* __restrict__ offs,
  int* __restrict__ fill, int* __restrict__ slot_tok, int* __restrict__ tok_slots)
{
  int t = blockIdx.x*256 + threadIdx.x;
  if (t >= TT) return;
  #pragma unroll
  for (int j = 0; j < 2; ++j) {
    int e = topi[t*2+j];
    int p = atomicAdd(&fill[e], 1);
    int s = offs[e] + p;
    slot_tok[s] = t;
    tok_slots[t*2+j] = s;
  }
}

__global__ __launch_bounds__(256) void gather_k(const u16* __restrict__ x2, const int* __restrict__ slot_tok,
                                                u16* __restrict__ xg)
{
  int s = blockIdx.x;
  int t = slot_tok[s];
  const uint4* src = (const uint4*)(x2 + (size_t)t*HH);
  uint4* dst = (uint4*)(xg + (size_t)s*HH);
  dst[threadIdx.x] = src[threadIdx.x];
}

// ---------------- combine: out = hidden + w0*eo[s0] + w1*eo[s1] ----------------
__global__ __launch_bounds__(256) void combine_k(const float* __restrict__ hidden, const u16* __restrict__ eo,
  const int* __restrict__ tok_slots, const float* __restrict__ topw, float* __restrict__ out)
{
  int gid = blockIdx.x*256 + threadIdx.x;
  int t = gid >> 9;
  int c4 = (gid & 511) * 4;
  int s0 = tok_slots[t*2], s1 = tok_slots[t*2+1];
  float w0 = topw[t*2], w1 = topw[t*2+1];
  const float* hp = hidden + (size_t)t*HH + c4;
  const u16* a = eo + (size_t)s0*HH + c4;
  const u16* b = eo + (size_t)s1*HH + c4;
  float* op = out + (size_t)t*HH + c4;
  #pragma unroll
  for (int j = 0; j < 4; ++j)
    op[j] = hp[j] + w0*b2f(a[j]) + w1*b2f(b[j]);
}

// ---------------- launch ----------------
extern "C" void kernel_launch(void* const* d_in, const int* in_sizes, int n_in,
                              void* d_out, int out_size, void* d_ws, size_t ws_size,
                              hipStream_t stream)
{
  (void)in_sizes; (void)n_in; (void)out_size; (void)ws_size;
  const float* hs     = (const float*)d_in[0];
  const int*   pos    = (const int*)d_in[1];
  const float* ln1    = (const float*)d_in[2];
  const float* ln2    = (const float*)d_in[3];
  const float* wq     = (const float*)d_in[4];
  const float* wk     = (const float*)d_in[5];
  const float* wv     = (const float*)d_in[6];
  const float* wo     = (const float*)d_in[7];
  const float* rw     = (const float*)d_in[8];
  const float* wg     = (const float*)d_in[9];
  const float* wu     = (const float*)d_in[10];
  const float* wd     = (const float*)d_in[11];
  const float* wsgt   = (const float*)d_in[12];
  const float* wsup   = (const float*)d_in[13];
  const float* wsdn   = (const float*)d_in[14];
  const float* wsg    = (const float*)d_in[15];
  float* out = (float*)d_out;
  char* ws = (char*)d_ws;

  const size_t MB = 1ull << 20;
  u16*   x1     = (u16*)(ws + 0);          // [0,8) — reused as atto later
  float* q_lin  = (float*)(ws + 8*MB);     // [8,24) — reused as x2/xg later
  float* k_lin  = (float*)(ws + 24*MB);    // [24,28)
  u16*   qb     = (u16*)(ws + 28*MB);      // [28,36)
  u16*   kb     = (u16*)(ws + 36*MB);      // [36,38)
  u16*   vb     = (u16*)(ws + 38*MB);      // [38,40)
  float* hidden = (float*)(ws + 40*MB);    // [40,56)
  u16*   atto   = (u16*)(ws + 0);          // reuse x1
  u16*   x2     = (u16*)(ws + 8*MB);       // reuse q_lin
  u16*   xg     = (u16*)(ws + 16*MB);      // reuse q_lin tail + k_lin + qb (dead)
  u16*   sg_g   = (u16*)(ws + 56*MB);      // [56,72)
  u16*   h2     = (u16*)(ws + 72*MB);      // [72,88)
  u16*   g      = (u16*)(ws + 88*MB);      // [88,120)
  u16*   h1     = (u16*)(ws + 120*MB);     // [120,152)
  u16*   eo     = (u16*)(ws + 152*MB);     // [152,168)
  char* sm = ws + 168*MB;
  int*   cnt      = (int*)(sm);
  int*   fill     = (int*)(sm + 32);
  int*   offs     = (int*)(sm + 64);
  int*   sched    = (int*)(sm + 128);
  int*   topi     = (int*)(sm + 1024);
  float* topw     = (float*)(sm + 1024 + 16384);
  int*   tok_slots= (int*)(sm + 1024 + 32768);
  int*   slot_tok = (int*)(sm + 1024 + 49152);
  float* sgate    = (float*)(sm + 1024 + 65536);

  hipMemsetAsync(cnt, 0, 64, stream);  // cnt[8] + fill[8]

  rmsnorm_k<<<TT, 256, 0, stream>>>(hs, ln1, x1);
  gemm_k<0,false><<<dim3(16,16), 256, 0, stream>>>(x1, wq, q_lin, nullptr, nullptr, TT, 2048, 2048, 0);
  gemm_k<0,false><<<dim3(4,16),  256, 0, stream>>>(x1, wk, k_lin, nullptr, nullptr, TT,  512, 2048, 0);
  gemm_k<1,false><<<dim3(4,16),  256, 0, stream>>>(x1, wv, vb,    nullptr, nullptr, TT,  512, 2048, 0);
  rope_k<<<(TT*NH*64)/256,  256, 0, stream>>>(q_lin, pos, qb, NH);
  rope_k<<<(TT*NKV*64)/256, 256, 0, stream>>>(k_lin, pos, kb, NKV);
  attn_k<<<dim3(32,16), 256, 0, stream>>>(qb, kb, vb, atto);
  gemm_k<2,false><<<dim3(16,16), 256, 0, stream>>>(atto, wo, hidden, hs, nullptr, TT, 2048, 2048, 0);
  rmsnorm_k<<<TT, 256, 0, stream>>>(hidden, ln2, x2);
  router_k<<<TT, 256, 0, stream>>>(hidden, ln2, rw, wsg, topi, topw, cnt, sgate);
  sched_k<<<1, 1, 0, stream>>>(cnt, offs, sched);
  assign_k<<<8, 256, 0, stream>>>(topi, offs, fill, slot_tok, tok_slots);
  gather_k<<<4096, 256, 0, stream>>>(x2, slot_tok, xg);
  // shared expert
  gemm_k<1,false><<<dim3(32,16), 256, 0, stream>>>(x2, wsgt, sg_g, nullptr, nullptr, TT, 4096, 2048, 0);
  gemm_k<3,false><<<dim3(32,16), 256, 0, stream>>>(x2, wsup, h2, sg_g, nullptr, TT, 4096, 2048, 0);
  // MoE (scheduled per-expert blocks)
  gemm_k<1,true><<<dim3(32,40), 256, 0, stream>>>(xg, wg, g,  nullptr, sched, 0, 4096, 2048, (size_t)2048*4096);
  gemm_k<3,true><<<dim3(32,40), 256, 0, stream>>>(xg, wu, h1, g,       sched, 0, 4096, 2048, (size_t)2048*4096);
  gemm_k<1,true><<<dim3(16,40), 256, 0, stream>>>(h1, wd, eo, nullptr, sched, 0, 2048, 4096, (size_t)4096*2048);
  combine_k<<<4096, 256, 0, stream>>>(hidden, eo, tok_slots, topw, out);
  // shared-expert down-proj: out += sigmoid_gate[row] * (h2 @ ws_down)
  gemm_k<4,false><<<dim3(16,16), 256, 0, stream>>>(h2, wsdn, out, sgate, nullptr, TT, 2048, 4096, 0);
}